// Round 15
// baseline (331.130 us; speedup 1.0000x reference)
//
#include <hip/hip_runtime.h>
#include <stdint.h>

#define S_DIM 8192
#define IN_DIM 4096
#define OUT_DIM 4096
#define K_EXT 128
#define SCALING 0.5f

typedef __attribute__((ext_vector_type(4))) float f32x4;
typedef __attribute__((ext_vector_type(8))) __bf16 bf16x8;

__device__ __forceinline__ unsigned short f2bf(float f) {
    union { float f; uint32_t u; } v; v.f = f;
    uint32_t u = v.u;
    u += 0x7fffu + ((u >> 16) & 1u);   // RNE
    return (unsigned short)(u >> 16);
}

__device__ __forceinline__ bf16x8 cvt8(float4 lo, float4 hi) {
    union { bf16x8 v; unsigned short u[8]; } r;
    r.u[0] = f2bf(lo.x); r.u[1] = f2bf(lo.y); r.u[2] = f2bf(lo.z); r.u[3] = f2bf(lo.w);
    r.u[4] = f2bf(hi.x); r.u[5] = f2bf(hi.y); r.u[6] = f2bf(hi.z); r.u[7] = f2bf(hi.w);
    return r.v;
}

// ---- Kernel 1: merged prep + xak ----
// blocks 0..255   : xak — x f32->bf16 + xe[s][a*16+r] = (a==widx[s]) ? x[s,:].A[a,r,:] : 0
//                   (A converted inline from f32; L2-resident)
// blocks 256..1279: prep — W->bf16 and we[o][a*16+r] = bf16(0.5*B[a][o][r]) (grid-stride)
__global__ __launch_bounds__(512) void pxk(const float* __restrict__ x,
                                           const float* __restrict__ W,
                                           const float* __restrict__ A,
                                           const float* __restrict__ B,
                                           const int* __restrict__ widx,
                                           unsigned short* __restrict__ xbf,
                                           unsigned short* __restrict__ wbf,
                                           unsigned short* __restrict__ we,
                                           unsigned short* __restrict__ xe) {
    __shared__ unsigned short xs[2][32 * 64];    // 2 x 4 KB, swizzled
    __shared__ unsigned short as_[2][128 * 64];  // 2 x 16 KB, swizzled

    if (blockIdx.x >= 256) {
        // ---------------- prep path ----------------
        int tid = (blockIdx.x - 256) * 512 + threadIdx.x;
        const int stride = 1024 * 512;
        const int nW4 = (OUT_DIM * IN_DIM) / 4;
        for (int i = tid; i < nW4; i += stride) {
            float4 v = ((const float4*)W)[i];
            ushort4 o;
            o.x = f2bf(v.x); o.y = f2bf(v.y); o.z = f2bf(v.z); o.w = f2bf(v.w);
            ((ushort4*)wbf)[i] = o;
        }
        for (int j = tid; j < OUT_DIM * 8; j += stride) {
            int o = j >> 3, a = j & 7;
            const float* src = B + ((size_t)a * OUT_DIM + o) * 16;
            unsigned short* dst = we + (size_t)o * K_EXT + a * 16;
#pragma unroll
            for (int r = 0; r < 16; r += 4) {
                float4 v = *(const float4*)(src + r);
                ushort4 u;
                u.x = f2bf(SCALING * v.x); u.y = f2bf(SCALING * v.y);
                u.z = f2bf(SCALING * v.z); u.w = f2bf(SCALING * v.w);
                *(ushort4*)(dst + r) = u;
            }
        }
        return;
    }

    // ---------------- xak path (R14 double-buffered pipeline, A from f32 inline) ----------------
    int s0 = blockIdx.x * 32;
    int t = threadIdx.x;
    int lane = t & 63, w = t >> 6;
    int wr = w & 1, wc = w >> 1;
    int frow = lane & 15, koct = lane >> 4;

    f32x4 acc[2];
#pragma unroll
    for (int n = 0; n < 2; ++n)
#pragma unroll
        for (int j = 0; j < 4; ++j) acc[n][j] = 0.f;

    int xrow = t >> 4, xf4 = t & 15;
    const float* xsrc = x + (size_t)(s0 + xrow) * IN_DIM + xf4 * 4;
    unsigned short* xdst = xbf + (size_t)(s0 + xrow) * IN_DIM + xf4 * 4;
    int xsd = xrow * 64 + ((xf4 * 4) ^ ((xrow & 7) << 3));

    // A staging: chunks c0 = t (aj=t>>3, ch=t&7) and c1 = 512+t; sources are f32
    int aj0 = t >> 3, ch0 = t & 7;
    int aj1 = (512 + t) >> 3, ch1 = t & 7;
    const float* Asrc0 = A + (size_t)aj0 * IN_DIM + ch0 * 8;
    const float* Asrc1 = A + (size_t)aj1 * IN_DIM + ch1 * 8;
    int asd0 = aj0 * 64 + ((ch0 ^ (aj0 & 7)) << 3);
    int asd1 = aj1 * 64 + ((ch1 ^ (aj1 & 7)) << 3);

    int xr_ = wr * 16 + frow;
    int xi0 = xr_ * 64 + ((koct ^ (xr_ & 7)) << 3);
    int xi1 = xr_ * 64 + (((koct + 4) ^ (xr_ & 7)) << 3);
    int ar0_ = wc * 32 + frow, ar1_ = wc * 32 + 16 + frow;
    int ai00 = ar0_ * 64 + ((koct ^ (ar0_ & 7)) << 3);
    int ai01 = ar0_ * 64 + (((koct + 4) ^ (ar0_ & 7)) << 3);
    int ai10 = ar1_ * 64 + ((koct ^ (ar1_ & 7)) << 3);
    int ai11 = ar1_ * 64 + (((koct + 4) ^ (ar1_ & 7)) << 3);

#define XSTORE(P_, K0_, XV_, A0L_, A0H_, A1L_, A1H_) do { \
    ushort4 o_; \
    o_.x = f2bf(XV_.x); o_.y = f2bf(XV_.y); o_.z = f2bf(XV_.z); o_.w = f2bf(XV_.w); \
    *(ushort4*)(xdst + (K0_)) = o_; \
    *(ushort4*)&xs[P_][xsd] = o_; \
    *(bf16x8*)&as_[P_][asd0] = cvt8(A0L_, A0H_); \
    *(bf16x8*)&as_[P_][asd1] = cvt8(A1L_, A1H_); \
  } while (0)

#define XBODY(P_, KT_, LD_) do { \
    float4 xv_, a0l_, a0h_, a1l_, a1h_; \
    if (LD_) { \
        xv_ = *(const float4*)(xsrc + ((KT_) + 1) * 64); \
        a0l_ = *(const float4*)(Asrc0 + ((KT_) + 1) * 64); \
        a0h_ = *(const float4*)(Asrc0 + ((KT_) + 1) * 64 + 4); \
        a1l_ = *(const float4*)(Asrc1 + ((KT_) + 1) * 64); \
        a1h_ = *(const float4*)(Asrc1 + ((KT_) + 1) * 64 + 4); \
    } \
    bf16x8 xf0_ = *(const bf16x8*)&xs[P_][xi0]; \
    bf16x8 xf1_ = *(const bf16x8*)&xs[P_][xi1]; \
    bf16x8 a00_ = *(const bf16x8*)&as_[P_][ai00]; \
    bf16x8 a01_ = *(const bf16x8*)&as_[P_][ai01]; \
    bf16x8 a10_ = *(const bf16x8*)&as_[P_][ai10]; \
    bf16x8 a11_ = *(const bf16x8*)&as_[P_][ai11]; \
    acc[0] = __builtin_amdgcn_mfma_f32_16x16x32_bf16(xf0_, a00_, acc[0], 0, 0, 0); \
    acc[0] = __builtin_amdgcn_mfma_f32_16x16x32_bf16(xf1_, a01_, acc[0], 0, 0, 0); \
    acc[1] = __builtin_amdgcn_mfma_f32_16x16x32_bf16(xf0_, a10_, acc[1], 0, 0, 0); \
    acc[1] = __builtin_amdgcn_mfma_f32_16x16x32_bf16(xf1_, a11_, acc[1], 0, 0, 0); \
    if (LD_) XSTORE((P_) ^ 1, ((KT_) + 1) * 64, xv_, a0l_, a0h_, a1l_, a1h_); \
    __syncthreads(); \
  } while (0)

    {
        float4 xv = *(const float4*)xsrc;
        float4 a0l = *(const float4*)Asrc0;
        float4 a0h = *(const float4*)(Asrc0 + 4);
        float4 a1l = *(const float4*)Asrc1;
        float4 a1h = *(const float4*)(Asrc1 + 4);
        XSTORE(0, 0, xv, a0l, a0h, a1l, a1h);
    }
    __syncthreads();

#pragma unroll 1
    for (int kt2 = 0; kt2 < 32; ++kt2) {
        int kt = kt2 * 2;
        XBODY(0, kt, 1);
        XBODY(1, kt + 1, (kt2 < 31));
    }

#pragma unroll
    for (int rg = 0; rg < 4; ++rg) {
        int s = s0 + wr * 16 + koct * 4 + rg;
        int aidx = widx[s];
#pragma unroll
        for (int nn = 0; nn < 2; ++nn) {
            int a = wc * 2 + nn;
            unsigned short v = (a == aidx) ? f2bf(acc[nn][rg]) : (unsigned short)0;
            xe[(size_t)s * K_EXT + a * 16 + frow] = v;
        }
    }
}

// ------- Kernel 2: 256x256 GEMM over K=4224, kh-split halves, 1 half-tile stage/phase, vmcnt(6) -------
// (byte-identical to rounds 11/13/14)
__device__ __forceinline__ void gload_lds16(const void* g, void* l) {
    __builtin_amdgcn_global_load_lds(
        (const __attribute__((address_space(1))) unsigned int*)(uintptr_t)g,
        (__attribute__((address_space(3))) unsigned int*)(unsigned int)(uintptr_t)l,
        16, 0, 0);
}

#define VM8 asm volatile("s_waitcnt vmcnt(8)" ::: "memory")
#define VM6 asm volatile("s_waitcnt vmcnt(6)" ::: "memory")
#define VM4 asm volatile("s_waitcnt vmcnt(4)" ::: "memory")
#define VM0 asm volatile("s_waitcnt vmcnt(0)" ::: "memory")
#define VMNOP do {} while (0)
#define BAR do { __builtin_amdgcn_s_barrier(); asm volatile("" ::: "memory"); } while (0)

__global__ __launch_bounds__(512, 2) void gemm256(const unsigned short* __restrict__ Xb,
                                                  const unsigned short* __restrict__ Wb,
                                                  const unsigned short* __restrict__ Xe,
                                                  const unsigned short* __restrict__ We,
                                                  const float* __restrict__ bias,
                                                  float* __restrict__ out) {
    extern __shared__ unsigned short lds[];

    const int nT = 512;
    int bid = blockIdx.x;
    int swz = (bid & 7) * (nT >> 3) + (bid >> 3);
    int tm = swz >> 4, tn = swz & 15;
    int rowBase = tm * 256, colBase = tn * 256;

    int t = threadIdx.x;
    int lane = t & 63;
    int wid = t >> 6;
    int wm = wid >> 2;
    int wn = wid & 3;
    int frow = lane & 15;
    int koct = lane >> 4;
    int wmBase = wm * 128, wnBase = wn * 64;

    int slotA = ((wm << 2) | koct) ^ (frow & 7);
    int slotB = (((wn >> 1) << 2) | koct) ^ (frow & 7);
    const unsigned short* pA0 = lds + frow * 64 + slotA * 8;
    const unsigned short* pA1 = pA0 + 32768;
    const unsigned short* pB0 = lds + 8192 + (wn & 1) * 4096 + frow * 64 + slotB * 8;
    const unsigned short* pB1 = pB0 + 32768;

    int sg = (t & 7) ^ ((t >> 3) & 7);
    int rr = (t >> 3) + ((sg >> 2) << 7);
    int cc = (sg & 3) << 3;
    uint32_t oB0 = (uint32_t)(rr * IN_DIM + cc);
    uint32_t oB1 = oB0 + 64 * IN_DIM;
    uint32_t oE0 = (uint32_t)(rr * K_EXT + cc);
    uint32_t oE1 = oE0 + 64 * K_EXT;
    const unsigned short* aBase = Xb + (size_t)rowBase * IN_DIM;
    const unsigned short* bBase = Wb + (size_t)colBase * IN_DIM;
    const unsigned short* aeBase = Xe + (size_t)rowBase * K_EXT;
    const unsigned short* beBase = We + (size_t)colBase * K_EXT;

    f32x4 acc[8][4];
#pragma unroll
    for (int m = 0; m < 8; m++)
#pragma unroll
        for (int n = 0; n < 4; n++)
#pragma unroll
            for (int j = 0; j < 4; j++) acc[m][n][j] = 0.f;

#define RDA(P_, KH_, MH_, DST) \
    _Pragma("unroll") for (int mm = 0; mm < 4; ++mm) \
      DST[mm] = *(const bf16x8*)(pA##P_ + (KH_) * 16384 + (MH_) * 4096 + mm * 1024);
#define RDB(P_, KH_, DST) \
    _Pragma("unroll") for (int nn = 0; nn < 4; ++nn) \
      DST[nn] = *(const bf16x8*)(pB##P_ + (KH_) * 16384 + nn * 1024);
#define MFMA16(AF, BF, MH_) \
    __builtin_amdgcn_s_setprio(1); \
    _Pragma("unroll") for (int mm = 0; mm < 4; ++mm) \
      _Pragma("unroll") for (int nn = 0; nn < 4; ++nn) \
        acc[(MH_) * 4 + mm][nn] = __builtin_amdgcn_mfma_f32_16x16x32_bf16( \
            AF[mm], BF[nn], acc[(MH_) * 4 + mm][nn], 0, 0, 0); \
    __builtin_amdgcn_s_setprio(0);

#define STG(BASE_, O0_, O1_, KO_, LDSO_) do { \
    gload_lds16((BASE_) + (KO_) + (O0_), &lds[(LDSO_) + t * 8]); \
    gload_lds16((BASE_) + (KO_) + (O1_), &lds[(LDSO_) + 4096 + t * 8]); \
  } while (0)

#define TILE(P_, A1_, B1_, X0_, X1_, K1_, S1_, A2_, B2_, Y0_, Y1_, K2_, S2_, VA_, VB_) do { \
    bf16x8 aF[4], bF[4]; \
    RDA(P_, 0, 0, aF); RDB(P_, 0, bF); \
    if (S1_) STG(A1_, X0_, X1_, K1_, ((P_ ^ 1) * 32768 + 16384)); \
    VA_; BAR; MFMA16(aF, bF, 0); BAR; \
    RDA(P_, 0, 1, aF); \
    if (S1_) STG(B1_, X0_, X1_, K1_, ((P_ ^ 1) * 32768 + 24576)); \
    BAR; MFMA16(aF, bF, 1); BAR; \
    RDA(P_, 1, 0, aF); RDB(P_, 1, bF); \
    if (S2_) STG(A2_, Y0_, Y1_, K2_, ((P_) * 32768 + 0)); \
    VB_; BAR; MFMA16(aF, bF, 0); BAR; \
    RDA(P_, 1, 1, aF); \
    if (S2_) STG(B2_, Y0_, Y1_, K2_, ((P_) * 32768 + 8192)); \
    BAR; MFMA16(aF, bF, 1); BAR; \
  } while (0)

    STG(aBase, oB0, oB1, 0, 0);
    STG(bBase, oB0, oB1, 0, 8192);
    STG(aBase, oB0, oB1, 32, 16384);
    STG(bBase, oB0, oB1, 32, 24576);
    STG(aBase, oB0, oB1, 64, 32768);
    STG(bBase, oB0, oB1, 64, 40960);
    VM8; BAR;

    int kel = 0;
#pragma unroll 1
    for (int it = 0; it < 31; ++it) {
        TILE(0, aBase, bBase, oB0, oB1, kel + 96, 1, aBase, bBase, oB0, oB1, kel + 128, 1, VM6, VM6); kel += 64;
        TILE(1, aBase, bBase, oB0, oB1, kel + 96, 1, aBase, bBase, oB0, oB1, kel + 128, 1, VM6, VM6); kel += 64;
    }
    TILE(0, aBase, bBase, oB0, oB1, 4064, 1, aeBase, beBase, oE0, oE1, 0, 1, VM6, VM6);   // 62
    TILE(1, aeBase, beBase, oE0, oE1, 32, 1, aeBase, beBase, oE0, oE1, 64, 1, VM6, VM6);  // 63
    TILE(0, aeBase, beBase, oE0, oE1, 96, 1, aBase, bBase, oB0, oB1, 0, 0, VM6, VM4);     // 64
    TILE(1, aBase, bBase, oB0, oB1, 0, 0, aBase, bBase, oB0, oB1, 0, 0, VM0, VMNOP);      // 65

    int rquad = koct << 2;
    float biasv[4];
#pragma unroll
    for (int n = 0; n < 4; n++) biasv[n] = bias[colBase + wnBase + n * 16 + frow];

#pragma unroll
    for (int m = 0; m < 8; m++) {
#pragma unroll
        for (int rg = 0; rg < 4; rg++) {
            int lr = wmBase + (m >> 2) * 64 + (m & 3) * 16 + rquad + rg;
            float* orow = out + (size_t)(rowBase + lr) * OUT_DIM;
#pragma unroll
            for (int n = 0; n < 4; n++) {
                int lc = wnBase + n * 16 + frow;
                orow[colBase + lc] = acc[m][n][rg] + biasv[n];
            }
        }
    }
}

extern "C" void kernel_launch(void* const* d_in, const int* in_sizes, int n_in,
                              void* d_out, int out_size, void* d_ws, size_t ws_size,
                              hipStream_t stream) {
    const float* x = (const float*)d_in[0];
    const float* W = (const float*)d_in[1];
    const float* bias = (const float*)d_in[2];
    const float* Abuf = (const float*)d_in[3];
    const float* Bbuf = (const float*)d_in[4];   // [1, A, OUT, R]
    const int* widx = (const int*)d_in[5];
    float* out = (float*)d_out;

    size_t xbf_elems = (size_t)S_DIM * IN_DIM;
    size_t wbf_elems = (size_t)OUT_DIM * IN_DIM;
    size_t xe_elems = (size_t)S_DIM * K_EXT;
    size_t we_elems = (size_t)OUT_DIM * K_EXT;
    size_t need = (xbf_elems + wbf_elems + xe_elems + we_elems) * 2;
    if (ws_size < need) return;

    unsigned short* xbf = (unsigned short*)d_ws;
    unsigned short* wbf = xbf + xbf_elems;
    unsigned short* xe = wbf + wbf_elems;
    unsigned short* we = xe + xe_elems;

    hipFuncSetAttribute(reinterpret_cast<const void*>(gemm256),
                        hipFuncAttributeMaxDynamicSharedMemorySize, 131072);

    pxk<<<1280, 512, 0, stream>>>(x, W, Abuf, Bbuf, widx, xbf, wbf, we, xe);
    gemm256<<<512, 512, 131072, stream>>>(xbf, wbf, xe, we, bias, out);
}

// Round 16
// 319.363 us; speedup vs baseline: 1.0368x; 1.0368x over previous
//
#include <hip/hip_runtime.h>
#include <stdint.h>

#define S_DIM 8192
#define IN_DIM 4096
#define OUT_DIM 4096
#define K_EXT 128
#define SCALING 0.5f

typedef __attribute__((ext_vector_type(4))) float f32x4;
typedef __attribute__((ext_vector_type(8))) __bf16 bf16x8;

__device__ __forceinline__ unsigned short f2bf(float f) {
    union { float f; uint32_t u; } v; v.f = f;
    uint32_t u = v.u;
    u += 0x7fffu + ((u >> 16) & 1u);   // RNE
    return (unsigned short)(u >> 16);
}

// ---- Kernel 1: fused prep: W->bf16, A->bf16, we[o][a*16+r] = bf16(0.5*B[a][o][r]) ----
__global__ __launch_bounds__(256) void prep(const float* __restrict__ W,
                                            const float* __restrict__ A,
                                            const float* __restrict__ B,
                                            unsigned short* __restrict__ wbf,
                                            unsigned short* __restrict__ abf,
                                            unsigned short* __restrict__ we) {
    int tid = blockIdx.x * blockDim.x + threadIdx.x;
    int stride = gridDim.x * blockDim.x;
    const int nW4 = (OUT_DIM * IN_DIM) / 4;
    for (int i = tid; i < nW4; i += stride) {
        float4 v = ((const float4*)W)[i];
        ushort4 o;
        o.x = f2bf(v.x); o.y = f2bf(v.y); o.z = f2bf(v.z); o.w = f2bf(v.w);
        ((ushort4*)wbf)[i] = o;
    }
    const int nA4 = (8 * 16 * IN_DIM) / 4;
    for (int i = tid; i < nA4; i += stride) {
        float4 v = ((const float4*)A)[i];
        ushort4 o;
        o.x = f2bf(v.x); o.y = f2bf(v.y); o.z = f2bf(v.z); o.w = f2bf(v.w);
        ((ushort4*)abf)[i] = o;
    }
    for (int j = tid; j < OUT_DIM * 8; j += stride) {
        int o = j >> 3, a = j & 7;
        const float* src = B + ((size_t)a * OUT_DIM + o) * 16;
        unsigned short* dst = we + (size_t)o * K_EXT + a * 16;
#pragma unroll
        for (int r = 0; r < 16; r += 4) {
            float4 v = *(const float4*)(src + r);
            ushort4 u;
            u.x = f2bf(SCALING * v.x); u.y = f2bf(SCALING * v.y);
            u.z = f2bf(SCALING * v.z); u.w = f2bf(SCALING * v.w);
            *(ushort4*)(dst + r) = u;
        }
    }
}

// ------- Kernel 2: x f32->bf16 + xe[s][a*16+r] = (a==widx[s]) ? x[s,:].A[a,r,:] : 0 -------
// Double-buffered LDS, single barrier/iter, tile-t+1 loads issued before tile-t compute.
__global__ __launch_bounds__(512) void xak(const float* __restrict__ x,
                                           const unsigned short* __restrict__ Abf,
                                           const int* __restrict__ widx,
                                           unsigned short* __restrict__ xbf,
                                           unsigned short* __restrict__ xe) {
    __shared__ unsigned short xs[2][32 * 64];    // 2 x 4 KB, swizzled
    __shared__ unsigned short as_[2][128 * 64];  // 2 x 16 KB, swizzled
    int s0 = blockIdx.x * 32;
    int t = threadIdx.x;
    int lane = t & 63, w = t >> 6;
    int wr = w & 1, wc = w >> 1;
    int frow = lane & 15, koct = lane >> 4;

    f32x4 acc[2];
#pragma unroll
    for (int n = 0; n < 2; ++n)
#pragma unroll
        for (int j = 0; j < 4; ++j) acc[n][j] = 0.f;

    // x load/store/LDS indices (per-thread constant)
    int xrow = t >> 4, xf4 = t & 15;
    const float* xsrc = x + (size_t)(s0 + xrow) * IN_DIM + xf4 * 4;
    unsigned short* xdst = xbf + (size_t)(s0 + xrow) * IN_DIM + xf4 * 4;
    int xsd = xrow * 64 + ((xf4 * 4) ^ ((xrow & 7) << 3));

    // A staging: chunks c0 = t (aj=t>>3, ch=t&7) and c1 = 512+t
    int aj0 = t >> 3, ch0 = t & 7;
    int aj1 = (512 + t) >> 3, ch1 = t & 7;  // (512+t)&7 == t&7
    const unsigned short* Asrc0 = Abf + (size_t)aj0 * IN_DIM + ch0 * 8;
    const unsigned short* Asrc1 = Abf + (size_t)aj1 * IN_DIM + ch1 * 8;
    int asd0 = aj0 * 64 + ((ch0 ^ (aj0 & 7)) << 3);
    int asd1 = aj1 * 64 + ((ch1 ^ (aj1 & 7)) << 3);

    // LDS read indices (per-thread constant, per k-slot)
    int xr_ = wr * 16 + frow;
    int xi0 = xr_ * 64 + ((koct ^ (xr_ & 7)) << 3);
    int xi1 = xr_ * 64 + (((koct + 4) ^ (xr_ & 7)) << 3);
    int ar0_ = wc * 32 + frow, ar1_ = wc * 32 + 16 + frow;
    int ai00 = ar0_ * 64 + ((koct ^ (ar0_ & 7)) << 3);
    int ai01 = ar0_ * 64 + (((koct + 4) ^ (ar0_ & 7)) << 3);
    int ai10 = ar1_ * 64 + ((koct ^ (ar1_ & 7)) << 3);
    int ai11 = ar1_ * 64 + (((koct + 4) ^ (ar1_ & 7)) << 3);

#define XSTORE(P_, K0_, XV_, AV0_, AV1_) do { \
    ushort4 o_; \
    o_.x = f2bf(XV_.x); o_.y = f2bf(XV_.y); o_.z = f2bf(XV_.z); o_.w = f2bf(XV_.w); \
    *(ushort4*)(xdst + (K0_)) = o_; \
    *(ushort4*)&xs[P_][xsd] = o_; \
    *(bf16x8*)&as_[P_][asd0] = AV0_; \
    *(bf16x8*)&as_[P_][asd1] = AV1_; \
  } while (0)

#define XBODY(P_, KT_, LD_) do { \
    float4 xv_; bf16x8 av0_, av1_; \
    if (LD_) { \
        xv_ = *(const float4*)(xsrc + ((KT_) + 1) * 64); \
        av0_ = *(const bf16x8*)(Asrc0 + ((KT_) + 1) * 64); \
        av1_ = *(const bf16x8*)(Asrc1 + ((KT_) + 1) * 64); \
    } \
    bf16x8 xf0_ = *(const bf16x8*)&xs[P_][xi0]; \
    bf16x8 xf1_ = *(const bf16x8*)&xs[P_][xi1]; \
    bf16x8 a00_ = *(const bf16x8*)&as_[P_][ai00]; \
    bf16x8 a01_ = *(const bf16x8*)&as_[P_][ai01]; \
    bf16x8 a10_ = *(const bf16x8*)&as_[P_][ai10]; \
    bf16x8 a11_ = *(const bf16x8*)&as_[P_][ai11]; \
    acc[0] = __builtin_amdgcn_mfma_f32_16x16x32_bf16(xf0_, a00_, acc[0], 0, 0, 0); \
    acc[0] = __builtin_amdgcn_mfma_f32_16x16x32_bf16(xf1_, a01_, acc[0], 0, 0, 0); \
    acc[1] = __builtin_amdgcn_mfma_f32_16x16x32_bf16(xf0_, a10_, acc[1], 0, 0, 0); \
    acc[1] = __builtin_amdgcn_mfma_f32_16x16x32_bf16(xf1_, a11_, acc[1], 0, 0, 0); \
    if (LD_) XSTORE((P_) ^ 1, ((KT_) + 1) * 64, xv_, av0_, av1_); \
    __syncthreads(); \
  } while (0)

    // prologue: tile 0 into buf 0
    {
        float4 xv = *(const float4*)xsrc;
        bf16x8 av0 = *(const bf16x8*)Asrc0;
        bf16x8 av1 = *(const bf16x8*)Asrc1;
        XSTORE(0, 0, xv, av0, av1);
    }
    __syncthreads();

#pragma unroll 1
    for (int kt2 = 0; kt2 < 32; ++kt2) {
        int kt = kt2 * 2;
        XBODY(0, kt, 1);                 // compute tile kt, load/stage kt+1
        XBODY(1, kt + 1, (kt2 < 31));    // compute tile kt+1, load/stage kt+2
    }

#pragma unroll
    for (int rg = 0; rg < 4; ++rg) {
        int s = s0 + wr * 16 + koct * 4 + rg;
        int aidx = widx[s];
#pragma unroll
        for (int nn = 0; nn < 2; ++nn) {
            int a = wc * 2 + nn;
            unsigned short v = (a == aidx) ? f2bf(acc[nn][rg]) : (unsigned short)0;
            xe[(size_t)s * K_EXT + a * 16 + frow] = v;
        }
    }
}

// ------- Kernel 3: 256x256 GEMM over K=4224, kh-split halves, 1 half-tile stage/phase, vmcnt(6) -------
// (byte-identical to rounds 11/13/14)
__device__ __forceinline__ void gload_lds16(const void* g, void* l) {
    __builtin_amdgcn_global_load_lds(
        (const __attribute__((address_space(1))) unsigned int*)(uintptr_t)g,
        (__attribute__((address_space(3))) unsigned int*)(unsigned int)(uintptr_t)l,
        16, 0, 0);
}

#define VM8 asm volatile("s_waitcnt vmcnt(8)" ::: "memory")
#define VM6 asm volatile("s_waitcnt vmcnt(6)" ::: "memory")
#define VM4 asm volatile("s_waitcnt vmcnt(4)" ::: "memory")
#define VM0 asm volatile("s_waitcnt vmcnt(0)" ::: "memory")
#define VMNOP do {} while (0)
#define BAR do { __builtin_amdgcn_s_barrier(); asm volatile("" ::: "memory"); } while (0)

__global__ __launch_bounds__(512, 2) void gemm256(const unsigned short* __restrict__ Xb,
                                                  const unsigned short* __restrict__ Wb,
                                                  const unsigned short* __restrict__ Xe,
                                                  const unsigned short* __restrict__ We,
                                                  const float* __restrict__ bias,
                                                  float* __restrict__ out) {
    extern __shared__ unsigned short lds[];

    const int nT = 512;
    int bid = blockIdx.x;
    int swz = (bid & 7) * (nT >> 3) + (bid >> 3);
    int tm = swz >> 4, tn = swz & 15;
    int rowBase = tm * 256, colBase = tn * 256;

    int t = threadIdx.x;
    int lane = t & 63;
    int wid = t >> 6;
    int wm = wid >> 2;
    int wn = wid & 3;
    int frow = lane & 15;
    int koct = lane >> 4;
    int wmBase = wm * 128, wnBase = wn * 64;

    int slotA = ((wm << 2) | koct) ^ (frow & 7);
    int slotB = (((wn >> 1) << 2) | koct) ^ (frow & 7);
    const unsigned short* pA0 = lds + frow * 64 + slotA * 8;
    const unsigned short* pA1 = pA0 + 32768;
    const unsigned short* pB0 = lds + 8192 + (wn & 1) * 4096 + frow * 64 + slotB * 8;
    const unsigned short* pB1 = pB0 + 32768;

    int sg = (t & 7) ^ ((t >> 3) & 7);
    int rr = (t >> 3) + ((sg >> 2) << 7);
    int cc = (sg & 3) << 3;
    uint32_t oB0 = (uint32_t)(rr * IN_DIM + cc);
    uint32_t oB1 = oB0 + 64 * IN_DIM;
    uint32_t oE0 = (uint32_t)(rr * K_EXT + cc);
    uint32_t oE1 = oE0 + 64 * K_EXT;
    const unsigned short* aBase = Xb + (size_t)rowBase * IN_DIM;
    const unsigned short* bBase = Wb + (size_t)colBase * IN_DIM;
    const unsigned short* aeBase = Xe + (size_t)rowBase * K_EXT;
    const unsigned short* beBase = We + (size_t)colBase * K_EXT;

    f32x4 acc[8][4];
#pragma unroll
    for (int m = 0; m < 8; m++)
#pragma unroll
        for (int n = 0; n < 4; n++)
#pragma unroll
            for (int j = 0; j < 4; j++) acc[m][n][j] = 0.f;

#define RDA(P_, KH_, MH_, DST) \
    _Pragma("unroll") for (int mm = 0; mm < 4; ++mm) \
      DST[mm] = *(const bf16x8*)(pA##P_ + (KH_) * 16384 + (MH_) * 4096 + mm * 1024);
#define RDB(P_, KH_, DST) \
    _Pragma("unroll") for (int nn = 0; nn < 4; ++nn) \
      DST[nn] = *(const bf16x8*)(pB##P_ + (KH_) * 16384 + nn * 1024);
#define MFMA16(AF, BF, MH_) \
    __builtin_amdgcn_s_setprio(1); \
    _Pragma("unroll") for (int mm = 0; mm < 4; ++mm) \
      _Pragma("unroll") for (int nn = 0; nn < 4; ++nn) \
        acc[(MH_) * 4 + mm][nn] = __builtin_amdgcn_mfma_f32_16x16x32_bf16( \
            AF[mm], BF[nn], acc[(MH_) * 4 + mm][nn], 0, 0, 0); \
    __builtin_amdgcn_s_setprio(0);

#define STG(BASE_, O0_, O1_, KO_, LDSO_) do { \
    gload_lds16((BASE_) + (KO_) + (O0_), &lds[(LDSO_) + t * 8]); \
    gload_lds16((BASE_) + (KO_) + (O1_), &lds[(LDSO_) + 4096 + t * 8]); \
  } while (0)

#define TILE(P_, A1_, B1_, X0_, X1_, K1_, S1_, A2_, B2_, Y0_, Y1_, K2_, S2_, VA_, VB_) do { \
    bf16x8 aF[4], bF[4]; \
    RDA(P_, 0, 0, aF); RDB(P_, 0, bF); \
    if (S1_) STG(A1_, X0_, X1_, K1_, ((P_ ^ 1) * 32768 + 16384)); \
    VA_; BAR; MFMA16(aF, bF, 0); BAR; \
    RDA(P_, 0, 1, aF); \
    if (S1_) STG(B1_, X0_, X1_, K1_, ((P_ ^ 1) * 32768 + 24576)); \
    BAR; MFMA16(aF, bF, 1); BAR; \
    RDA(P_, 1, 0, aF); RDB(P_, 1, bF); \
    if (S2_) STG(A2_, Y0_, Y1_, K2_, ((P_) * 32768 + 0)); \
    VB_; BAR; MFMA16(aF, bF, 0); BAR; \
    RDA(P_, 1, 1, aF); \
    if (S2_) STG(B2_, Y0_, Y1_, K2_, ((P_) * 32768 + 8192)); \
    BAR; MFMA16(aF, bF, 1); BAR; \
  } while (0)

    STG(aBase, oB0, oB1, 0, 0);
    STG(bBase, oB0, oB1, 0, 8192);
    STG(aBase, oB0, oB1, 32, 16384);
    STG(bBase, oB0, oB1, 32, 24576);
    STG(aBase, oB0, oB1, 64, 32768);
    STG(bBase, oB0, oB1, 64, 40960);
    VM8; BAR;

    int kel = 0;
#pragma unroll 1
    for (int it = 0; it < 31; ++it) {
        TILE(0, aBase, bBase, oB0, oB1, kel + 96, 1, aBase, bBase, oB0, oB1, kel + 128, 1, VM6, VM6); kel += 64;
        TILE(1, aBase, bBase, oB0, oB1, kel + 96, 1, aBase, bBase, oB0, oB1, kel + 128, 1, VM6, VM6); kel += 64;
    }
    TILE(0, aBase, bBase, oB0, oB1, 4064, 1, aeBase, beBase, oE0, oE1, 0, 1, VM6, VM6);   // 62
    TILE(1, aeBase, beBase, oE0, oE1, 32, 1, aeBase, beBase, oE0, oE1, 64, 1, VM6, VM6);  // 63
    TILE(0, aeBase, beBase, oE0, oE1, 96, 1, aBase, bBase, oB0, oB1, 0, 0, VM6, VM4);     // 64
    TILE(1, aBase, bBase, oB0, oB1, 0, 0, aBase, bBase, oB0, oB1, 0, 0, VM0, VMNOP);      // 65

    int rquad = koct << 2;
    float biasv[4];
#pragma unroll
    for (int n = 0; n < 4; n++) biasv[n] = bias[colBase + wnBase + n * 16 + frow];

#pragma unroll
    for (int m = 0; m < 8; m++) {
#pragma unroll
        for (int rg = 0; rg < 4; rg++) {
            int lr = wmBase + (m >> 2) * 64 + (m & 3) * 16 + rquad + rg;
            float* orow = out + (size_t)(rowBase + lr) * OUT_DIM;
#pragma unroll
            for (int n = 0; n < 4; n++) {
                int lc = wnBase + n * 16 + frow;
                orow[colBase + lc] = acc[m][n][rg] + biasv[n];
            }
        }
    }
}

extern "C" void kernel_launch(void* const* d_in, const int* in_sizes, int n_in,
                              void* d_out, int out_size, void* d_ws, size_t ws_size,
                              hipStream_t stream) {
    const float* x = (const float*)d_in[0];
    const float* W = (const float*)d_in[1];
    const float* bias = (const float*)d_in[2];
    const float* Abuf = (const float*)d_in[3];
    const float* Bbuf = (const float*)d_in[4];   // [1, A, OUT, R]
    const int* widx = (const int*)d_in[5];
    float* out = (float*)d_out;

    size_t xbf_elems = (size_t)S_DIM * IN_DIM;
    size_t wbf_elems = (size_t)OUT_DIM * IN_DIM;
    size_t abf_elems = (size_t)8 * 16 * IN_DIM;
    size_t xe_elems = (size_t)S_DIM * K_EXT;
    size_t we_elems = (size_t)OUT_DIM * K_EXT;
    size_t need = (xbf_elems + wbf_elems + abf_elems + xe_elems + we_elems) * 2;
    if (ws_size < need) return;

    unsigned short* xbf = (unsigned short*)d_ws;
    unsigned short* wbf = xbf + xbf_elems;
    unsigned short* abf = wbf + wbf_elems;
    unsigned short* xe = abf + abf_elems;
    unsigned short* we = xe + xe_elems;

    hipFuncSetAttribute(reinterpret_cast<const void*>(gemm256),
                        hipFuncAttributeMaxDynamicSharedMemorySize, 131072);

    prep<<<2048, 256, 0, stream>>>(W, Abuf, Bbuf, wbf, abf, we);
    xak<<<256, 512, 0, stream>>>(x, abf, widx, xbf, xe);
    gemm256<<<512, 512, 131072, stream>>>(xbf, wbf, xe, we, bias, out);
}